// Round 12
// baseline (579.489 us; speedup 1.0000x reference)
//
#include <hip/hip_runtime.h>

#define IN_SIZE 256
#define OUT_SIZE 64
#define N_NODES 512
#define FAN_IN 32
#define T_DIM 2048
#define D_DIM 832
#define TOTAL_EDGE 16384
#define BLK_F4 1088   // per-node: 1024 f4 butterfly pairs + 64 f4 entries
#define MAX_ENT 64
#define THRESH -20.0f

typedef const __attribute__((address_space(1))) void gas_t;
typedef __attribute__((address_space(3))) void las_t;
__device__ __forceinline__ void lds_dma16(const float4* g, const float4* l,
                                          int lane) {
  __builtin_amdgcn_global_load_lds((gas_t*)(g + lane), (las_t*)l, 16, 0, 0);
}

// DPP wave64 sums (lane 63 ends with total) — validated rounds 3..11
template <int CTRL, int RM>
__device__ __forceinline__ float dppadd(float v) {
  int m = __builtin_amdgcn_update_dpp(0, __float_as_int(v), CTRL, RM, 0xf, true);
  return v + __int_as_float(m);
}
template <int CTRL, int RM>
__device__ __forceinline__ void dpps4(float& a, float& b, float& c, float& d) {
  a = dppadd<CTRL, RM>(a);
  b = dppadd<CTRL, RM>(b);
  c = dppadd<CTRL, RM>(c);
  d = dppadd<CTRL, RM>(d);
}
__device__ __forceinline__ void wave_sum4(float& a, float& b, float& c,
                                          float& d) {
  dpps4<0x111, 0xf>(a, b, c, d);
  dpps4<0x112, 0xf>(a, b, c, d);
  dpps4<0x114, 0xf>(a, b, c, d);
  dpps4<0x118, 0xf>(a, b, c, d);
  dpps4<0x142, 0xa>(a, b, c, d);
  dpps4<0x143, 0xc>(a, b, c, d);
}
__device__ __forceinline__ float rl63(float v) {
  return __int_as_float(__builtin_amdgcn_readlane(__float_as_int(v), 63));
}

// ---------------------------------------------------------------------------
// KV build — r10's validated version.
// ---------------------------------------------------------------------------
__global__ __launch_bounds__(256) void kv_kernel(
    const float* __restrict__ actives, const int* __restrict__ in_idxs,
    const float* __restrict__ weights, float2* __restrict__ KVd) {
  __shared__ float rows[8][833];
  __shared__ int s_idx[64 * FAN_IN];
  __shared__ float2 s_w[64 * FAN_IN];
  int tid = threadIdx.x;
  int tb = blockIdx.x * 8;
  for (int i = tid; i < 8 * D_DIM; i += 256) {
    int r = i / D_DIM, c = i - r * D_DIM;
    int t = tb + r;
    rows[r][c] = (t < T_DIM - 1) ? actives[(size_t)(t + 1) * D_DIM + c] : 0.f;
  }
  int tl = tid & 7, ng = tid >> 3;
  for (int tile = 0; tile < 8; ++tile) {
    __syncthreads();
    int n0 = tile * 64;
    for (int i = tid; i < 64 * FAN_IN; i += 256) {
      int g = n0 * FAN_IN + i;
      s_idx[i] = in_idxs[g];
      const float* wp = weights + (size_t)g * 3;
      s_w[i] = make_float2(wp[1], wp[2]);
    }
    __syncthreads();
#pragma unroll
    for (int it = 0; it < 2; ++it) {
      int nl = ng + 32 * it;
      const int* ip = &s_idx[nl * FAN_IN];
      const float2* wp = &s_w[nl * FAN_IN];
      float k = 0.f, v = 0.f;
#pragma unroll 8
      for (int f = 0; f < FAN_IN; ++f) {
        float a = rows[tl][ip[f]];
        float2 w = wp[f];
        k = fmaf(w.x, a, k);
        v = fmaf(w.y, a, v);
      }
      KVd[(size_t)(n0 + nl) * (2 * BLK_F4) + tb + tl] = make_float2(k, v);
    }
  }
}

// ---------------------------------------------------------------------------
// Block build — r10's validated version (entries c>node only).
// ---------------------------------------------------------------------------
__global__ __launch_bounds__(256) void block_kernel(
    const float* __restrict__ x, const int* __restrict__ in_idxs,
    const float* __restrict__ weights, float4* __restrict__ blk,
    float4* __restrict__ meta_g, float4* __restrict__ Qb) {
  __shared__ float2 skv[T_DIM], sbk[T_DIM];
  __shared__ int hist[64];
  __shared__ float smx[4], smn[4];
  __shared__ float4 sEnt[MAX_ENT];
  __shared__ int ecnt;
  int node = blockIdx.x, tid = threadIdx.x;
  if (tid == 0) ecnt = 0;
  const float2* src = (const float2*)(blk + (size_t)node * BLK_F4);
  float mx = -3.4e38f, mn = 3.4e38f;
#pragma unroll
  for (int j = 0; j < 8; ++j) {
    int t = j * 256 + tid;
    float2 kv = (t < 2047) ? src[t] : make_float2(0.f, 0.f);
    skv[t] = kv;
    if (t < 2047) { mx = fmaxf(mx, kv.x); mn = fminf(mn, kv.x); }
  }
  if (tid < 64) hist[tid] = 0;
#pragma unroll
  for (int off = 32; off > 0; off >>= 1) {
    mx = fmaxf(mx, __shfl_xor(mx, off));
    mn = fminf(mn, __shfl_xor(mn, off));
  }
  if ((tid & 63) == 0) { smx[tid >> 6] = mx; smn[tid >> 6] = mn; }
  __syncthreads();
  float kmax = fmaxf(fmaxf(smx[0], smx[1]), fmaxf(smx[2], smx[3]));
  float kmin = fminf(fminf(smn[0], smn[1]), fminf(smn[2], smn[3]));
  float invbw = 64.0f / (kmax - kmin);
#pragma unroll
  for (int j = 0; j < 8; ++j) {
    int t = j * 256 + tid;
    if (t < 2047) {
      int b = (int)((skv[t].x - kmin) * invbw);
      b = b < 0 ? 0 : (b > 63 ? 63 : b);
      atomicAdd(&hist[b], 1);
    }
  }
  {
    int target = IN_SIZE + node;
    for (int e = tid; e < TOTAL_EDGE; e += 256) {
      if (in_idxs[e] == target) {
        int c = e >> 5;
        if (c > node) {
          int p = atomicAdd(&ecnt, 1);
          if (p < MAX_ENT) {
            const float* wp = weights + (size_t)e * 3;
            sEnt[p] = make_float4(__int_as_float(c), wp[0], wp[1], wp[2]);
          }
        }
      }
    }
  }
  __syncthreads();
  if (tid < 64) {
    int v = hist[tid];
    int incl = v;
#pragma unroll
    for (int d = 1; d < 64; d <<= 1) {
      int u = __shfl_up(incl, d);
      if (tid >= d) incl += u;
    }
    hist[tid] = incl - v;
  }
  if (tid == 0) sbk[2047] = make_float2(0.f, 0.f);
  __syncthreads();
#pragma unroll
  for (int j = 0; j < 8; ++j) {
    int t = j * 256 + tid;
    if (t < 2047) {
      int b = (int)((skv[t].x - kmin) * invbw);
      b = b < 0 ? 0 : (b > 63 ? 63 : b);
      int p = atomicAdd(&hist[b], 1);
      sbk[p] = skv[t];
    }
  }
  if (tid < 32) {
    int g = node * FAN_IN + tid;
    int idx = in_idxs[g];
    const float* wp = weights + (size_t)g * 3;
    float a = (idx < IN_SIZE) ? x[idx] : 0.f;
    float p0 = a * wp[0], p1 = a * wp[1], p2 = a * wp[2];
#pragma unroll
    for (int off = 16; off > 0; off >>= 1) {
      p0 += __shfl_xor(p0, off);
      p1 += __shfl_xor(p1, off);
      p2 += __shfl_xor(p2, off);
    }
    if (tid == 0) Qb[node] = make_float4(p0, p1, p2, 0.f);
  }
  __syncthreads();
  float4* B = blk + (size_t)node * BLK_F4;
  for (int i = tid; i < 1024; i += 256) {
    float2 a = sbk[i];
    float2 d = sbk[2046 - i];
    B[i] = make_float4(a.x, a.y, d.x, d.y);
  }
  int cnt = ecnt < MAX_ENT ? ecnt : MAX_ENT;
  if (tid < MAX_ENT)
    B[1024 + tid] = (tid < cnt) ? sEnt[tid] : make_float4(0.f, 0.f, 0.f, 0.f);
  if (tid == 0)
    meta_g[3 * node + 0] =
        make_float4(kmax, kmin, __int_as_float(cnt), sbk[64].x);
  if (tid == 1)
    meta_g[3 * node + 1] =
        make_float4(sbk[1982].x, sbk[256].x, sbk[1790].x, sbk[512].x);
  if (tid == 2)
    meta_g[3 * node + 2] = make_float4(sbk[1534].x, 0.f, 0.f, 0.f);
}

// ---------------------------------------------------------------------------
// Level sweep v3: 1 block x 1024 thr (16 waves). r10's BF prologue + sort.
// Main loop: chunk0 for up to 32 nodes/level DMA'd into a double-buffered
// LDS ring one level ahead (global_load_lds cannot be sunk by the compiler;
// the level barrier's mandatory vmcnt(0) IS the completion wait, with ~1000
// cyc of process slack). Each wave processes 2 nodes interleaved (positions
// w and w+16) — no cold overflow round. ent/t1/t2/t3 global, issued right
// after predicates.
// ---------------------------------------------------------------------------
__global__ __launch_bounds__(1024) void sweep_kernel(
    const int* __restrict__ in_idxs, const float4* __restrict__ Qb,
    const float4* __restrict__ meta_g, const float4* __restrict__ blk,
    float* __restrict__ out) {
  __shared__ float4 sC0[2][32][64];  // 65536 B chunk0 ring
  __shared__ float4 sQKV[N_NODES];
  __shared__ float4 sMeta[N_NODES][3];
  __shared__ int sLevel[N_NODES];
  __shared__ int sOrder[N_NODES];
  __shared__ int sStart[N_NODES + 1];
  __shared__ int sCur[N_NODES];
  __shared__ int wtot[8];
  __shared__ int sFlag, sNlev;
  __shared__ float souts[OUT_SIZE];
  const int tid = threadIdx.x;
  const int lane = tid & 63;
  const int w = tid >> 6;

  for (int n = tid; n < N_NODES; n += 1024) {
    sQKV[n] = Qb[n];
    sMeta[n][0] = meta_g[3 * n + 0];
    sMeta[n][1] = meta_g[3 * n + 1];
    sMeta[n][2] = meta_g[3 * n + 2];
    sLevel[n] = 0;
  }
  if (tid == 0) { sFlag = 1; sNlev = 1; }
  int pidx[32];
  if (tid < N_NODES) {
    const int4* ip = (const int4*)(in_idxs + tid * FAN_IN);
#pragma unroll
    for (int j = 0; j < 8; ++j) {
      int4 v = ip[j];
      pidx[4 * j + 0] = v.x; pidx[4 * j + 1] = v.y;
      pidx[4 * j + 2] = v.z; pidx[4 * j + 3] = v.w;
    }
  }
  __syncthreads();

  // ---- level relaxation (r10's validated Bellman-Ford) ----
  bool again = true;
  while (again) {
    if (tid == 0) sFlag = 0;
    __syncthreads();
    bool ch = false;
    if (tid < N_NODES) {
      int nl = 0;
#pragma unroll
      for (int f = 0; f < FAN_IN; ++f) {
        int p = pidx[f] - IN_SIZE;
        if (p >= 0 && p < tid) {
          int lp = sLevel[p] + 1;
          nl = nl > lp ? nl : lp;
        }
      }
      if (nl > sLevel[tid]) { sLevel[tid] = nl; ch = true; }
    }
    if (ch) sFlag = 1;
    __syncthreads();
    again = (sFlag != 0);
  }

  // ---- counting sort by level (r10's validated version) ----
  for (int i = tid; i < N_NODES; i += 1024) sCur[i] = 0;
  __syncthreads();
  if (tid < N_NODES) {
    atomicAdd(&sCur[sLevel[tid]], 1);
    atomicMax(&sNlev, sLevel[tid] + 1);
  }
  __syncthreads();
  int incl = 0;
  if (tid < N_NODES) {
    incl = sCur[tid];
#pragma unroll
    for (int d = 1; d < 64; d <<= 1) {
      int u = __shfl_up(incl, d);
      if ((tid & 63) >= d) incl += u;
    }
    if ((tid & 63) == 63) wtot[tid >> 6] = incl;
  }
  __syncthreads();
  if (tid < N_NODES) {
    int add = 0;
    for (int ww = 0; ww < (tid >> 6); ++ww) add += wtot[ww];
    sStart[tid + 1] = incl + add;
    if (tid == 0) sStart[0] = 0;
  }
  __syncthreads();
  for (int i = tid; i < N_NODES; i += 1024) sCur[i] = sStart[i];
  __syncthreads();
  if (tid < N_NODES) {
    int p = atomicAdd(&sCur[sLevel[tid]], 1);
    sOrder[p] = tid;
  }
  __syncthreads();
  const int nlev = sNlev;

  // dual-node interleaved process; nX < 0 => inert (no loads, no effects)
  auto process2 = [&](int nA, float4 c0A, int nB, float4 c0B) {
    float4 m0A = make_float4(0, 0, 0, 0), m1A = m0A, m2A = m0A, qvA = m0A;
    float4 m0B = m0A, m1B = m0A, m2B = m0A, qvB = m0A;
    if (nA >= 0) {
      qvA = sQKV[nA]; m0A = sMeta[nA][0]; m1A = sMeta[nA][1]; m2A = sMeta[nA][2];
    }
    if (nB >= 0) {
      qvB = sQKV[nB]; m0B = sMeta[nB][0]; m1B = sMeta[nB][1]; m2B = sMeta[nB][2];
    }
    float qA = qvA.x, klA = qvA.y, vlA = qvA.z;
    float qB = qvB.x, klB = qvB.y, vlB = qvB.z;
    int cntA = (nA >= 0) ? __float_as_int(m0A.z) : 0;
    int cntB = (nB >= 0) ? __float_as_int(m0B.z) : 0;
    float mA = fmaxf(fmaxf(qA * m0A.x, qA * m0A.y), qA * klA);
    float mB = fmaxf(fmaxf(qB * m0B.x, qB * m0B.y), qB * klB);
    bool p1A = nA >= 0 && (fmaxf(qA * m0A.w, qA * m1A.x) - mA >= THRESH);
    bool p2A = p1A && (fmaxf(qA * m1A.y, qA * m1A.z) - mA >= THRESH);
    bool p3A = p2A && (fmaxf(qA * m1A.w, qA * m2A.x) - mA >= THRESH);
    bool p1B = nB >= 0 && (fmaxf(qB * m0B.w, qB * m1B.x) - mB >= THRESH);
    bool p2B = p1B && (fmaxf(qB * m1B.y, qB * m1B.z) - mB >= THRESH);
    bool p3B = p2B && (fmaxf(qB * m1B.w, qB * m2B.x) - mB >= THRESH);
    const float4* BA = blk + (size_t)(nA >= 0 ? nA : 0) * BLK_F4;
    const float4* BB = blk + (size_t)(nB >= 0 ? nB : 0) * BLK_F4;
    // issue global loads early (ent always; tails under predicates)
    float4 entA, entB;
    entA = (nA >= 0) ? BA[1024 + lane] : make_float4(0, 0, 0, 0);
    entB = (nB >= 0) ? BB[1024 + lane] : make_float4(0, 0, 0, 0);
    float4 t1A[3], t2A[4], t3A[8], t1B[3], t2B[4], t3B[8];
    if (p1A) {
#pragma unroll
      for (int t = 0; t < 3; ++t) t1A[t] = BA[64 + 64 * t + lane];
    }
    if (p1B) {
#pragma unroll
      for (int t = 0; t < 3; ++t) t1B[t] = BB[64 + 64 * t + lane];
    }
    if (p2A) {
#pragma unroll
      for (int t = 0; t < 4; ++t) t2A[t] = BA[256 + 64 * t + lane];
    }
    if (p2B) {
#pragma unroll
      for (int t = 0; t < 4; ++t) t2B[t] = BB[256 + 64 * t + lane];
    }
    if (p3A) {
#pragma unroll
      for (int t = 0; t < 8; ++t) t3A[t] = BA[512 + 64 * t + lane];
    }
    if (p3B) {
#pragma unroll
      for (int t = 0; t < 8; ++t) t3B[t] = BB[512 + 64 * t + lane];
    }
    float elA = __expf(qA * klA - mA);
    float elB = __expf(qB * klB - mB);
    // chunk0 from LDS ring (prefetched by DMA)
    float wa0 = __expf(fmaf(qA, c0A.x, -mA));
    float wa1 = __expf(fmaf(qA, c0A.z, -mA));
    float swA = wa0 + wa1;
    float svA = fmaf(wa0, c0A.y, wa1 * c0A.w);
    float wb0 = __expf(fmaf(qB, c0B.x, -mB));
    float wb1 = __expf(fmaf(qB, c0B.z, -mB));
    float swB = wb0 + wb1;
    float svB = fmaf(wb0, c0B.y, wb1 * c0B.w);
    if (p1A) {
#pragma unroll
      for (int t = 0; t < 3; ++t) {
        float a0 = __expf(fmaf(qA, t1A[t].x, -mA));
        float a1 = __expf(fmaf(qA, t1A[t].z, -mA));
        swA += a0 + a1;
        svA = fmaf(a0, t1A[t].y, fmaf(a1, t1A[t].w, svA));
      }
    }
    if (p1B) {
#pragma unroll
      for (int t = 0; t < 3; ++t) {
        float a0 = __expf(fmaf(qB, t1B[t].x, -mB));
        float a1 = __expf(fmaf(qB, t1B[t].z, -mB));
        swB += a0 + a1;
        svB = fmaf(a0, t1B[t].y, fmaf(a1, t1B[t].w, svB));
      }
    }
    if (p2A) {
#pragma unroll
      for (int t = 0; t < 4; ++t) {
        float a0 = __expf(fmaf(qA, t2A[t].x, -mA));
        float a1 = __expf(fmaf(qA, t2A[t].z, -mA));
        swA += a0 + a1;
        svA = fmaf(a0, t2A[t].y, fmaf(a1, t2A[t].w, svA));
      }
    }
    if (p2B) {
#pragma unroll
      for (int t = 0; t < 4; ++t) {
        float a0 = __expf(fmaf(qB, t2B[t].x, -mB));
        float a1 = __expf(fmaf(qB, t2B[t].z, -mB));
        swB += a0 + a1;
        svB = fmaf(a0, t2B[t].y, fmaf(a1, t2B[t].w, svB));
      }
    }
    if (p3A) {
#pragma unroll
      for (int t = 0; t < 8; ++t) {
        float a0 = __expf(fmaf(qA, t3A[t].x, -mA));
        float a1 = __expf(fmaf(qA, t3A[t].z, -mA));
        if (t == 7 && lane == 63) a1 = 0.f;  // pair 1023 desc = median dup
        swA += a0 + a1;
        svA = fmaf(a0, t3A[t].y, fmaf(a1, t3A[t].w, svA));
      }
    }
    if (p3B) {
#pragma unroll
      for (int t = 0; t < 8; ++t) {
        float a0 = __expf(fmaf(qB, t3B[t].x, -mB));
        float a1 = __expf(fmaf(qB, t3B[t].z, -mB));
        if (t == 7 && lane == 63) a1 = 0.f;
        swB += a0 + a1;
        svB = fmaf(a0, t3B[t].y, fmaf(a1, t3B[t].w, svB));
      }
    }
    wave_sum4(swA, svA, swB, svB);
    float SA = rl63(swA) + elA;
    float SVA = fmaf(elA, vlA, rl63(svA));
    float SB = rl63(swB) + elB;
    float SVB = fmaf(elB, vlB, rl63(svB));
    float zA = SVA * __builtin_amdgcn_rcpf(SA);
    float zB = SVB * __builtin_amdgcn_rcpf(SB);
    float eoA = __expf(2.f * zA);
    float eoB = __expf(2.f * zB);
    float oA = 1.f - 2.f * __builtin_amdgcn_rcpf(eoA + 1.f);
    float oB = 1.f - 2.f * __builtin_amdgcn_rcpf(eoB + 1.f);
    if (nA >= 0 && lane == 0 && nA >= N_NODES - OUT_SIZE)
      souts[nA - (N_NODES - OUT_SIZE)] = oA;
    if (nB >= 0 && lane == 0 && nB >= N_NODES - OUT_SIZE)
      souts[nB - (N_NODES - OUT_SIZE)] = oB;
    if (lane < cntA) {
      int n = __float_as_int(entA.x);
      atomicAdd(&sQKV[n].x, oA * entA.y);
      atomicAdd(&sQKV[n].y, oA * entA.z);
      atomicAdd(&sQKV[n].z, oA * entA.w);
    }
    if (lane < cntB) {
      int n = __float_as_int(entB.x);
      atomicAdd(&sQKV[n].x, oB * entB.y);
      atomicAdd(&sQKV[n].y, oB * entB.z);
      atomicAdd(&sQKV[n].z, oB * entB.w);
    }
  };

  // prime level 0 chunk0 DMA into buffer 0 (sOrder valid after sort barrier)
  {
    int e0 = sStart[1];
#pragma unroll
    for (int pos = w; pos < 32; pos += 16) {
      int j = pos;  // sStart[0] == 0
      if (j < e0) lds_dma16(blk + (size_t)sOrder[j] * BLK_F4, &sC0[0][pos][0], lane);
    }
  }
  __syncthreads();  // drains prime DMA

  for (int L = 0; L < nlev; ++L) {
    int cb = L & 1, nb = cb ^ 1;
    int sL = sStart[L], eL = sStart[L + 1];
    // 1. DMA next level's chunk0 into the other buffer (wave-uniform branches)
    if (L + 1 < nlev) {
      int sN = eL, eN = sStart[L + 2 <= N_NODES ? L + 2 : N_NODES];
#pragma unroll
      for (int pos = w; pos < 32; pos += 16) {
        int j = sN + pos;
        if (j < eN)
          lds_dma16(blk + (size_t)sOrder[j] * BLK_F4, &sC0[nb][pos][0], lane);
      }
    }
    // 2. process current level: wave w -> positions w and w+16
    {
      int jA = sL + w, jB = sL + w + 16;
      int nA = (jA < eL) ? sOrder[jA] : -1;
      int nB = (jB < eL) ? sOrder[jB] : -1;
      process2(nA, sC0[cb][w][lane], nB, sC0[cb][w + 16][lane]);
    }
    // 3. safety overflow (width > 32): fully on-demand (~never)
    for (int i = sL + 32 + w; i < eL; i += 16) {
      int n2 = sOrder[i];
      process2(n2, blk[(size_t)n2 * BLK_F4 + lane], -1,
               make_float4(0, 0, 0, 0));
    }
    __syncthreads();  // scatters visible + next-level DMA drained
  }
  if (tid < OUT_SIZE) out[tid] = souts[tid];
}

// ---------------------------------------------------------------------------
extern "C" void kernel_launch(void* const* d_in, const int* in_sizes, int n_in,
                              void* d_out, int out_size, void* d_ws,
                              size_t ws_size, hipStream_t stream) {
  const float* x = (const float*)d_in[0];
  const float* actives = (const float*)d_in[1];
  const float* weights = (const float*)d_in[2];
  const int* in_idxs = (const int*)d_in[3];
  float* out = (float*)d_out;

  // workspace (~9.0 MB): blk | meta_g | Qb
  char* ws = (char*)d_ws;
  float4* blk = (float4*)ws;  // 512 * 1088 * 16 = 8,912,896 B
  size_t off = (size_t)N_NODES * BLK_F4 * 16;
  float4* meta_g = (float4*)(ws + off); off += (size_t)N_NODES * 3 * 16;
  float4* Qb = (float4*)(ws + off);

  kv_kernel<<<T_DIM / 8, 256, 0, stream>>>(actives, in_idxs, weights,
                                           (float2*)blk);
  block_kernel<<<N_NODES, 256, 0, stream>>>(x, in_idxs, weights, blk, meta_g,
                                            Qb);
  sweep_kernel<<<1, 1024, 0, stream>>>(in_idxs, Qb, meta_g, blk, out);
}